// Round 1
// 104.625 us; speedup vs baseline: 1.0521x; 1.0521x over previous
//
#include <hip/hip_runtime.h>
#include <stdint.h>

// Problem constants (from reference): x [2048][1024] f32, W [1024][4096] f32,
// out [2048][4096] f32 = x@W - 0.5*(||x_b||^2 + ||w_o||^2)
#define BATCH 2048
#define DIN   1024
#define DOUT  4096

// ---------- helpers ----------

// fp32 -> bf16 bits, round-to-nearest-even (inputs are finite normals; no NaN path)
__device__ __forceinline__ ushort f2bf(float f) {
    uint32_t u = __float_as_uint(f);
    u += 0x7fffu + ((u >> 16) & 1u);
    return (ushort)(u >> 16);
}

// async global->LDS direct copy, 16B per lane. LDS dest must be wave-uniform;
// HW writes lane i's 16B at ldsbase + i*16 (guide §5, m97/m104).
__device__ __forceinline__ void async_copy16(const void* gsrc, void* ldst) {
    __builtin_amdgcn_global_load_lds(
        reinterpret_cast<uint32_t __attribute__((address_space(1)))*>(
            reinterpret_cast<uintptr_t>(gsrc)),
        reinterpret_cast<uint32_t __attribute__((address_space(3)))*>(
            reinterpret_cast<uintptr_t>(ldst)),
        16, 0, 0);
}

typedef __bf16 bf16x8 __attribute__((ext_vector_type(8)));
typedef float  f32x4  __attribute__((ext_vector_type(4)));

// ---------- prep kernels ----------

// One block per row of x: cast to bf16, compute row sum of squares in fp32.
__global__ __launch_bounds__(256) void prep_x(const float* __restrict__ x,
                                              ushort* __restrict__ xb,
                                              float* __restrict__ xsq) {
    const int row = blockIdx.x;
    const int t = threadIdx.x;
    const float4 v = *(const float4*)(x + (size_t)row * DIN + t * 4);
    ushort4 pk;
    pk.x = f2bf(v.x); pk.y = f2bf(v.y); pk.z = f2bf(v.z); pk.w = f2bf(v.w);
    *(ushort4*)(xb + (size_t)row * DIN + t * 4) = pk;

    float s = v.x * v.x + v.y * v.y + v.z * v.z + v.w * v.w;
    #pragma unroll
    for (int off = 32; off > 0; off >>= 1) s += __shfl_down(s, off);
    __shared__ float ws[4];
    if ((t & 63) == 0) ws[t >> 6] = s;
    __syncthreads();
    if (t == 0) xsq[row] = ws[0] + ws[1] + ws[2] + ws[3];
}

// Transpose W [DIN][DOUT] f32 -> WbT [DOUT][DIN] bf16 via LDS 64x64 tile.
// float4 reads (16B/lane), ushort4 writes (8B/lane, coalesced 128B segments
// per 16-lane group). wsq reduced in LDS first: 64 global atomics per block.
__global__ __launch_bounds__(256) void prep_w(const float* __restrict__ W,
                                              ushort* __restrict__ wbt,
                                              float* __restrict__ wsq) {
    __shared__ float tile[64][65];  // +1 pad: 2-way max on both access patterns
    __shared__ float csum[64];
    const int o0 = blockIdx.x * 64;  // 64 blocks over DOUT
    const int i0 = blockIdx.y * 64;  // 16 blocks over DIN
    const int t  = threadIdx.x;
    const int c4 = (t & 15) * 4;     // 4-wide column group
    const int r0 = t >> 4;           // 0..15, +p*16 per pass

    if (t < 64) csum[t] = 0.f;
    __syncthreads();

    float ss0 = 0.f, ss1 = 0.f, ss2 = 0.f, ss3 = 0.f;
    #pragma unroll
    for (int p = 0; p < 4; ++p) {    // read coalesced rows of W, float4
        const int r = r0 + p * 16;
        const float4 v = *(const float4*)&W[(size_t)(i0 + r) * DOUT + o0 + c4];
        tile[r][c4 + 0] = v.x; tile[r][c4 + 1] = v.y;
        tile[r][c4 + 2] = v.z; tile[r][c4 + 3] = v.w;
        ss0 += v.x * v.x; ss1 += v.y * v.y;
        ss2 += v.z * v.z; ss3 += v.w * v.w;
    }
    atomicAdd(&csum[c4 + 0], ss0);
    atomicAdd(&csum[c4 + 1], ss1);
    atomicAdd(&csum[c4 + 2], ss2);
    atomicAdd(&csum[c4 + 3], ss3);
    __syncthreads();                 // tile complete + csum final
    if (t < 64) atomicAdd(&wsq[o0 + t], csum[t]);

    #pragma unroll
    for (int p = 0; p < 4; ++p) {    // write coalesced rows of W^T, ushort4
        const int orow = r0 + p * 16;
        ushort4 pk;
        pk.x = f2bf(tile[c4 + 0][orow]);
        pk.y = f2bf(tile[c4 + 1][orow]);
        pk.z = f2bf(tile[c4 + 2][orow]);
        pk.w = f2bf(tile[c4 + 3][orow]);
        *(ushort4*)&wbt[(size_t)(o0 + orow) * DIN + i0 + c4] = pk;
    }
}

// ---------- GEMM + epilogue ----------
// A = xb [BATCH][DIN] bf16, Bt = wbt [DOUT][DIN] bf16 (W^T), out fp32.
// 128x128 tile, BK=64, double-buffered LDS, ONE barrier per K-tile with
// next-tile prefetch overlapped under ds_read+MFMA (catalog T3 minimum
// 2-phase). LDS rows are 128B -> XOR-swizzle 16B chunks (slot ^= row&7),
// applied both-sides (rule 21): linear global_load_lds dest + pre-swizzled
// global SOURCE col + swizzled ds_read slot.
#define BM 128
#define BN 128
#define BK 64
#define NT (DIN / BK)  // 16 K-tiles

__global__ __launch_bounds__(256, 2) void gemm_bt_epi(
    const ushort* __restrict__ A,
    const ushort* __restrict__ Bt,
    const float* __restrict__ xsq,
    const float* __restrict__ wsq,
    float* __restrict__ out) {
    __shared__ __align__(16) ushort sA[2][BM * BK];  // 2 x 16 KiB
    __shared__ __align__(16) ushort sB[2][BN * BK];  // 2 x 16 KiB

    const int tid  = threadIdx.x;
    const int wv   = tid >> 6;
    const int lane = tid & 63;
    const int wr = wv >> 1, wc = wv & 1;
    const int m0 = blockIdx.y * BM;
    const int n0 = blockIdx.x * BN;

    // ---- staging geometry ----
    // Tile row-major [128][64] ushort (128B row = 8 chunks of 16B).
    // Dest chunk (linear, HW order): c = q*256 + tid; row = c>>3, slot = tid&7.
    // LDS(row, slot) must hold global chunk (slot ^ (row&7)) -> pre-swizzle src.
    const int srow = tid >> 3;                           // 0..31, +q*32
    const int scol = (((tid & 7) ^ (srow & 7)) << 3);    // swizzled k-offset (ushorts)
    const ushort* ag = A  + (size_t)(m0 + srow) * DIN + scol;
    const ushort* bg = Bt + (size_t)(n0 + srow) * DIN + scol;

    // ---- fragment geometry ----
    // A-op lane holds A[m=lane&15][k=(lane>>4)*8+j] (verified layout, kept).
    // Logical slot for k-step ks: ks*4 + (lane>>4); physical = ^ (row&7),
    // row&7 == lane&7 for all fragment rows (row = base + i*16 + (lane&15)).
    const int fr  = lane & 15;
    const int q4  = lane >> 4;
    const int x7  = lane & 7;
    const int arow = wr * 64 + fr;
    const int brow = wc * 64 + fr;
    const int sl0 = ((q4)     ^ x7) << 3;  // ushort offset within row, ks=0
    const int sl1 = ((4 + q4) ^ x7) << 3;  // ks=1

    f32x4 acc[4][4] = {};

    auto stage = [&](int b, int kt) {
        ushort* da = &sA[b][0] + wv * 512;   // wave-uniform base, HW adds lane*16B
        ushort* db = &sB[b][0] + wv * 512;
        #pragma unroll
        for (int q = 0; q < 4; ++q) {
            async_copy16(ag + (size_t)q * 32 * DIN + kt, da + q * 2048);
            async_copy16(bg + (size_t)q * 32 * DIN + kt, db + q * 2048);
        }
    };

    stage(0, 0);
    __syncthreads();   // compiler emits vmcnt(0) drain before s_barrier
    int cur = 0;

    for (int t = 0; t < NT; ++t) {
        if (t + 1 < NT) stage(cur ^ 1, (t + 1) * BK);  // prefetch next K-tile

        const ushort* pa = &sA[cur][0];
        const ushort* pb = &sB[cur][0];
        bf16x8 fa[2][4], fb[2][4];
        #pragma unroll
        for (int i = 0; i < 4; ++i) {
            fa[0][i] = *(const bf16x8*)&pa[(arow + i * 16) * BK + sl0];
            fa[1][i] = *(const bf16x8*)&pa[(arow + i * 16) * BK + sl1];
            fb[0][i] = *(const bf16x8*)&pb[(brow + i * 16) * BK + sl0];
            fb[1][i] = *(const bf16x8*)&pb[(brow + i * 16) * BK + sl1];
        }

        #pragma unroll
        for (int ks = 0; ks < 2; ++ks)
            #pragma unroll
            for (int mi = 0; mi < 4; ++mi)
                #pragma unroll
                for (int ni = 0; ni < 4; ++ni)
                    acc[mi][ni] = __builtin_amdgcn_mfma_f32_16x16x32_bf16(
                        fa[ks][mi], fb[ks][ni], acc[mi][ni], 0, 0, 0);

        __syncthreads();  // vmcnt(0): prefetched tile landed; all waves done
                          // reading buf[cur] (their lgkmcnt(0) preceded MFMA)
        cur ^= 1;
    }

    // Epilogue. C/D layout (measured m89/m91): col = lane&15, row = (lane>>4)*4 + r.
    const int er = (lane >> 4) * 4;
    const int ec = lane & 15;
    #pragma unroll
    for (int mi = 0; mi < 4; ++mi) {
        const int row = m0 + wr * 64 + mi * 16 + er;
        #pragma unroll
        for (int ni = 0; ni < 4; ++ni) {
            const int col = n0 + wc * 64 + ni * 16 + ec;
            const float wterm = wsq[col];
            #pragma unroll
            for (int r = 0; r < 4; ++r) {
                out[(size_t)(row + r) * DOUT + col] =
                    acc[mi][ni][r] - 0.5f * (xsq[row + r] + wterm);
            }
        }
    }
}

// ---------- launch ----------

extern "C" void kernel_launch(void* const* d_in, const int* in_sizes, int n_in,
                              void* d_out, int out_size, void* d_ws, size_t ws_size,
                              hipStream_t stream) {
    const float* x = (const float*)d_in[0];
    const float* W = (const float*)d_in[1];
    float* out = (float*)d_out;

    // Workspace layout (needs ~12.02 MiB):
    //   [0, 4MiB)        xb  : bf16 x   [2048][1024]
    //   [4MiB, 12MiB)    wbt : bf16 W^T [4096][1024]
    //   [12MiB, +8KiB)   xsq : f32 [2048]
    //   [+16KiB, +32KiB) wsq : f32 [4096]
    char* ws = (char*)d_ws;
    ushort* xb  = (ushort*)ws;
    ushort* wbt = (ushort*)(ws + (4u << 20));
    float*  xsq = (float*)(ws + (12u << 20));
    float*  wsq = (float*)(ws + (12u << 20) + (16u << 10));

    hipMemsetAsync(wsq, 0, DOUT * sizeof(float), stream);  // atomics target
    prep_x<<<BATCH, 256, 0, stream>>>(x, xb, xsq);
    prep_w<<<dim3(DOUT / 64, DIN / 64), 256, 0, stream>>>(W, wbt, wsq);
    gemm_bt_epi<<<dim3(DOUT / BN, BATCH / BM), 256, 0, stream>>>(xb, wbt, xsq, wsq, out);
}